// Round 1
// baseline (332.655 us; speedup 1.0000x reference)
//
#include <hip/hip_runtime.h>

typedef unsigned int uint;
typedef unsigned short ushort;

typedef __attribute__((ext_vector_type(8))) short bf16x8;
typedef __attribute__((ext_vector_type(4))) float f32x4;

#define TOK 256
#define OUTF 11008
#define INF 4096
#define BM 256
#define BN 32
#define BK 64
#define NKT 64  // INF / BK

__device__ __constant__ float NF4_TBL[16] = {
    -1.0f, -0.6961928009986877f, -0.5250730514526367f, -0.39491748809814453f,
    -0.28444138169288635f, -0.18477343022823334f, -0.09105003625154495f, 0.0f,
    0.07958029955625534f, 0.16093020141124725f, 0.24611230194568634f,
    0.33791524171829224f, 0.44070982933044434f, 0.5626170039176941f,
    0.7229568362236023f, 1.0f};

__device__ __forceinline__ ushort f2bf(float f) {
  return (ushort)((__float_as_uint(f) + 0x8000u) >> 16);
}

// async global->LDS, 16B per lane; lds base must be wave-uniform (lane*16 added by HW)
__device__ __forceinline__ void async_cp16(const void* g, void* l) {
  __builtin_amdgcn_global_load_lds(
      (const __attribute__((address_space(1))) uint*)g,
      (__attribute__((address_space(3))) uint*)l, 16, 0, 0);
}

// dequant 2 nf4 codes -> packed 2x bf16 (low = first code)
__device__ __forceinline__ uint dq2(int ca, int cb, float amax, int tbits) {
  float fa = __int_as_float(__builtin_amdgcn_ds_bpermute(ca << 2, tbits)) * amax;
  float fb = __int_as_float(__builtin_amdgcn_ds_bpermute(cb << 2, tbits)) * amax;
  uint ua = (__float_as_uint(fa) + 0x8000u) >> 16;
  uint ub = (__float_as_uint(fb) + 0x8000u) & 0xffff0000u;
  return ua | ub;
}

// kernel 1: x fp32 -> bf16 ; lora_B fp32 [OUTF,16] -> bf16 [OUTF,64] zero-padded
__global__ void prep_kernel(const float* __restrict__ x, const float* __restrict__ lB,
                            ushort* __restrict__ xbf, ushort* __restrict__ lBbf) {
  const int stride = gridDim.x * blockDim.x;
  for (int idx = blockIdx.x * blockDim.x + threadIdx.x; idx < TOK * INF; idx += stride)
    xbf[idx] = f2bf(x[idx]);
  for (int idx = blockIdx.x * blockDim.x + threadIdx.x; idx < OUTF * 64; idx += stride) {
    int n = idx >> 6, j = idx & 63;
    lBbf[idx] = (j < 16) ? f2bf(lB[n * 16 + j]) : (ushort)0;
  }
}

// kernel 2: xa2[m][j] = bf16( 2 * sum_k x[m][k]*lora_A[j][k] ), [TOK,64] zero-padded
__global__ void xa_kernel(const float* __restrict__ x, const float* __restrict__ lA,
                          ushort* __restrict__ xa2) {
  const int m = blockIdx.x;
  const int t = threadIdx.x;
  float acc[16];
#pragma unroll
  for (int j = 0; j < 16; ++j) acc[j] = 0.f;
  for (int kk = 0; kk < 16; ++kk) {
    int k = kk * 256 + t;
    float xv = x[m * INF + k];
#pragma unroll
    for (int j = 0; j < 16; ++j) acc[j] += xv * lA[j * INF + k];
  }
#pragma unroll
  for (int j = 0; j < 16; ++j)
#pragma unroll
    for (int s = 32; s > 0; s >>= 1) acc[j] += __shfl_xor(acc[j], s, 64);
  __shared__ float red[4][16];
  const int w = t >> 6, l = t & 63;
  if (l == 0) {
#pragma unroll
    for (int j = 0; j < 16; ++j) red[w][j] = acc[j];
  }
  __syncthreads();
  if (t < 64) {
    ushort v = 0;
    if (t < 16) {
      float s = red[0][t] + red[1][t] + red[2][t] + red[3][t];
      v = f2bf(2.0f * s);
    }
    xa2[m * 64 + t] = v;
  }
}

// kernel 3: main fused dequant GEMM + lora K-extension
__global__ __launch_bounds__(256, 2)
void gemm_kernel(const int* __restrict__ qc, const float* __restrict__ am,
                 const ushort* __restrict__ xbf, const ushort* __restrict__ lBbf,
                 const ushort* __restrict__ xa2, float* __restrict__ out) {
  __shared__ ushort Abuf[BM * BK];  // 32 KB, chunk-swizzled
  __shared__ ushort Bbuf[BN * BK];  // 4 KB, chunk-swizzled

  const int tid = threadIdx.x;
  const int w = tid >> 6;
  const int l = tid & 63;
  const int n0 = blockIdx.x * BN;

  const int tbits = __float_as_int(NF4_TBL[l & 15]);  // lanes 0..15 hold the table

  // A deposit geometry: issue i covers rows i*32 + w*8 + l/8; swizzled chunk on global side
  const int arow = w * 8 + (l >> 3);
  const int acol = ((l & 7) ^ (l >> 3)) << 3;  // element offset in [0,64)

  // B dequant geometry: 8 threads per row, 8 codes (= 1 chunk) each
  const int brow = tid >> 3;  // 0..31
  const int bq = tid & 7;     // chunk index 0..7

  // LDS fragment read offsets (ushort index), swizzle-matched
  int aoff[2][4], boff[2][2];
#pragma unroll
  for (int ks = 0; ks < 2; ++ks) {
    const int cc = ks * 4 + (l >> 4);
#pragma unroll
    for (int mt = 0; mt < 4; ++mt) {
      int row = w * 64 + mt * 16 + (l & 15);
      aoff[ks][mt] = row * 64 + ((cc ^ (l & 7)) << 3);
    }
#pragma unroll
    for (int nt = 0; nt < 2; ++nt) {
      int row = nt * 16 + (l & 15);
      boff[ks][nt] = row * 64 + ((cc ^ (l & 7)) << 3);
    }
  }

  f32x4 acc[4][2];
#pragma unroll
  for (int mt = 0; mt < 4; ++mt)
#pragma unroll
    for (int nt = 0; nt < 2; ++nt) acc[mt][nt] = (f32x4){0.f, 0.f, 0.f, 0.f};

  for (int kt = 0; kt <= NKT; ++kt) {
    if (kt < NKT) {
      // A: 8 async 1KB/wave issues -> 32 KB tile
#pragma unroll
      for (int i = 0; i < 8; ++i) {
        const ushort* g = xbf + (size_t)(i * 32 + arow) * INF + kt * BK + acol;
        async_cp16(g, &Abuf[(i * 256 + w * 64) * 8]);
      }
      // B: load 8 codes, dequant, 1x ds_write_b128
      const int* qrow = qc + (size_t)(n0 + brow) * INF + kt * BK + bq * 8;
      int4 c0 = ((const int4*)qrow)[0];
      int4 c1 = ((const int4*)qrow)[1];
      float amax = am[(n0 + brow) * 64 + kt];
      uint4 d;
      d.x = dq2(c0.x, c0.y, amax, tbits);
      d.y = dq2(c0.z, c0.w, amax, tbits);
      d.z = dq2(c1.x, c1.y, amax, tbits);
      d.w = dq2(c1.z, c1.w, amax, tbits);
      *(uint4*)&Bbuf[(brow * 8 + (bq ^ (brow & 7))) * 8] = d;
    } else {
      // lora extension: A tile from xa2 [256,64], B tile from lBbf rows [n0,n0+32)
#pragma unroll
      for (int i = 0; i < 8; ++i) {
        const ushort* g = xa2 + (i * 32 + arow) * 64 + acol;
        async_cp16(g, &Abuf[(i * 256 + w * 64) * 8]);
      }
      const ushort* g = lBbf + (size_t)(n0 + arow) * 64 + acol;
      async_cp16(g, &Bbuf[(w * 64) * 8]);
    }
    __syncthreads();
#pragma unroll
    for (int ks = 0; ks < 2; ++ks) {
      bf16x8 a[4], b[2];
#pragma unroll
      for (int mt = 0; mt < 4; ++mt) a[mt] = *(const bf16x8*)&Abuf[aoff[ks][mt]];
#pragma unroll
      for (int nt = 0; nt < 2; ++nt) b[nt] = *(const bf16x8*)&Bbuf[boff[ks][nt]];
#pragma unroll
      for (int mt = 0; mt < 4; ++mt)
#pragma unroll
        for (int nt = 0; nt < 2; ++nt)
          acc[mt][nt] = __builtin_amdgcn_mfma_f32_16x16x32_bf16(a[mt], b[nt], acc[mt][nt], 0, 0, 0);
    }
    __syncthreads();
  }

  // epilogue: C/D layout col=lane&15, row=(lane>>4)*4+reg
#pragma unroll
  for (int mt = 0; mt < 4; ++mt) {
#pragma unroll
    for (int nt = 0; nt < 2; ++nt) {
      int col = n0 + nt * 16 + (l & 15);
#pragma unroll
      for (int r = 0; r < 4; ++r) {
        int row = w * 64 + mt * 16 + (l >> 4) * 4 + r;
        out[(size_t)row * OUTF + col] = acc[mt][nt][r];
      }
    }
  }
}

extern "C" void kernel_launch(void* const* d_in, const int* in_sizes, int n_in,
                              void* d_out, int out_size, void* d_ws, size_t ws_size,
                              hipStream_t stream) {
  const float* x = (const float*)d_in[0];
  const int* qc = (const int*)d_in[1];
  const float* am = (const float*)d_in[2];
  const float* lA = (const float*)d_in[3];
  const float* lB = (const float*)d_in[4];
  float* out = (float*)d_out;

  ushort* xbf = (ushort*)d_ws;                    // TOK*INF bf16 = 2 MB
  ushort* lBbf = xbf + (size_t)TOK * INF;         // OUTF*64 bf16 = 1.34 MB
  ushort* xa2 = lBbf + (size_t)OUTF * 64;         // TOK*64 bf16 = 32 KB

  prep_kernel<<<1024, 256, 0, stream>>>(x, lB, xbf, lBbf);
  xa_kernel<<<TOK, 256, 0, stream>>>(x, lA, xa2);
  gemm_kernel<<<OUTF / BN, 256, 0, stream>>>(qc, am, xbf, lBbf, xa2, out);
}

// Round 3
// 318.190 us; speedup vs baseline: 1.0455x; 1.0455x over previous
//
#include <hip/hip_runtime.h>

typedef unsigned int uint;
typedef unsigned short ushort;

typedef __attribute__((ext_vector_type(8))) short bf16x8;
typedef __attribute__((ext_vector_type(4))) float f32x4;

#define TOK 256
#define OUTF 11008
#define INF 4096
#define BM 256
#define BN 32
#define BK 64
#define NKT 64    // INF / BK
#define NTILES 344  // OUTF / BN

__device__ __constant__ float NF4_TBL[16] = {
    -1.0f, -0.6961928009986877f, -0.5250730514526367f, -0.39491748809814453f,
    -0.28444138169288635f, -0.18477343022823334f, -0.09105003625154495f, 0.0f,
    0.07958029955625534f, 0.16093020141124725f, 0.24611230194568634f,
    0.33791524171829224f, 0.44070982933044434f, 0.5626170039176941f,
    0.7229568362236023f, 1.0f};

__device__ __forceinline__ ushort f2bf(float f) {
  return (ushort)((__float_as_uint(f) + 0x8000u) >> 16);
}

// async global->LDS, 16B per lane; lds base must be wave-uniform (lane*16 added by HW)
__device__ __forceinline__ void async_cp16(const void* g, void* l) {
  __builtin_amdgcn_global_load_lds(
      (const __attribute__((address_space(1))) uint*)g,
      (__attribute__((address_space(3))) uint*)l, 16, 0, 0);
}

// dequant 2 nf4 codes -> packed 2x bf16 (low = first code); table lives in lanes 0..15
__device__ __forceinline__ uint dq2(int ca, int cb, float amax, int tbits) {
  float fa = __int_as_float(__builtin_amdgcn_ds_bpermute(ca << 2, tbits)) * amax;
  float fb = __int_as_float(__builtin_amdgcn_ds_bpermute(cb << 2, tbits)) * amax;
  uint ua = (__float_as_uint(fa) + 0x8000u) >> 16;
  uint ub = (__float_as_uint(fb) + 0x8000u) & 0xffff0000u;
  return ua | ub;
}

// kernel 1: x fp32 -> bf16 (float4) ; lora_B fp32 [OUTF,16] -> bf16 [OUTF,64] zero-padded
__global__ void prep_kernel(const float4* __restrict__ x4, const float4* __restrict__ lB4,
                            ushort4* __restrict__ xbf4, ushort4* __restrict__ lBbf4) {
  const int stride = gridDim.x * blockDim.x;
  for (int idx = blockIdx.x * blockDim.x + threadIdx.x; idx < TOK * INF / 4; idx += stride) {
    float4 v = x4[idx];
    ushort4 o;
    o.x = f2bf(v.x); o.y = f2bf(v.y); o.z = f2bf(v.z); o.w = f2bf(v.w);
    xbf4[idx] = o;
  }
  for (int idx = blockIdx.x * blockDim.x + threadIdx.x; idx < OUTF * 16; idx += stride) {
    int n = idx >> 4, jq = idx & 15;
    ushort4 o = {0, 0, 0, 0};
    if (jq < 4) {
      float4 v = lB4[n * 4 + jq];
      o.x = f2bf(v.x); o.y = f2bf(v.y); o.z = f2bf(v.z); o.w = f2bf(v.w);
    }
    lBbf4[idx] = o;
  }
}

// kernel 2: xa2[m][j] = bf16( 2 * sum_k x[m][k]*lora_A[j][k] ), [TOK,64] zero-padded
// one block (1024 threads) per token; each thread owns one float4 strip of K
__global__ __launch_bounds__(1024)
void xa_kernel(const float* __restrict__ x, const float* __restrict__ lA,
               ushort* __restrict__ xa2) {
  const int m = blockIdx.x;
  const int t = threadIdx.x;
  const float4* x4 = (const float4*)(x + (size_t)m * INF);
  const float4* lA4 = (const float4*)lA;
  float4 xv = x4[t];
  float acc[16];
#pragma unroll
  for (int j = 0; j < 16; ++j) {
    float4 a = lA4[j * (INF / 4) + t];
    acc[j] = xv.x * a.x + xv.y * a.y + xv.z * a.z + xv.w * a.w;
  }
#pragma unroll
  for (int j = 0; j < 16; ++j)
#pragma unroll
    for (int s = 32; s > 0; s >>= 1) acc[j] += __shfl_xor(acc[j], s, 64);
  __shared__ float red[16][16];
  const int w = t >> 6, l = t & 63;
  if (l == 0) {
#pragma unroll
    for (int j = 0; j < 16; ++j) red[w][j] = acc[j];
  }
  __syncthreads();
  if (t < 64) {
    ushort v = 0;
    if (t < 16) {
      float s = 0.f;
#pragma unroll
      for (int w2 = 0; w2 < 16; ++w2) s += red[w2][t];
      v = f2bf(2.0f * s);
    }
    xa2[m * 64 + t] = v;
  }
}

// kernel 3: K-split fused dequant GEMM + lora K-extension (split 0 only)
__global__ __launch_bounds__(256, 4)
void gemm_kernel(const int* __restrict__ qc, const float* __restrict__ am,
                 const ushort* __restrict__ xbf, const ushort* __restrict__ lBbf,
                 const ushort* __restrict__ xa2, float* __restrict__ dest,
                 int kt_per) {
  __shared__ ushort Abuf[BM * BK];  // 32 KB, chunk-swizzled
  __shared__ ushort Bbuf[BN * BK];  // 4 KB, chunk-swizzled

  const int tid = threadIdx.x;
  const int w = tid >> 6;
  const int l = tid & 63;
  const int split = blockIdx.x / NTILES;
  const int ntile = blockIdx.x - split * NTILES;
  const int n0 = ntile * BN;
  const int k0t = split * kt_per;
  const int ktEnd = k0t + kt_per;

  const int tbits = __float_as_int(NF4_TBL[l & 15]);  // lanes 0..15 hold the table

  // A deposit geometry: issue i covers rows i*32 + w*8 + l/8; swizzled chunk on global side
  const int arow = w * 8 + (l >> 3);
  const int acol = ((l & 7) ^ (l >> 3)) << 3;  // element offset in [0,64)

  // B dequant geometry: 8 threads per row, 8 codes (= 1 chunk) each
  const int brow = tid >> 3;  // 0..31
  const int bq = tid & 7;     // chunk index 0..7

  // LDS fragment read offsets (ushort index), swizzle-matched
  int aoff[2][4], boff[2][2];
#pragma unroll
  for (int ks = 0; ks < 2; ++ks) {
    const int cc = ks * 4 + (l >> 4);
#pragma unroll
    for (int mt = 0; mt < 4; ++mt) {
      int row = w * 64 + mt * 16 + (l & 15);
      aoff[ks][mt] = row * 64 + ((cc ^ (l & 7)) << 3);
    }
#pragma unroll
    for (int nt = 0; nt < 2; ++nt) {
      int row = nt * 16 + (l & 15);
      boff[ks][nt] = row * 64 + ((cc ^ (l & 7)) << 3);
    }
  }

  f32x4 acc[4][2];
#pragma unroll
  for (int mt = 0; mt < 4; ++mt)
#pragma unroll
    for (int nt = 0; nt < 2; ++nt) acc[mt][nt] = (f32x4){0.f, 0.f, 0.f, 0.f};

  // software-prefetch q codes + absmax one iteration ahead (register pipeline)
  const int* qbase = qc + (size_t)(n0 + brow) * INF + bq * 8;
  const float* ambase = am + (size_t)(n0 + brow) * 64;
  int4 c0 = ((const int4*)(qbase + (size_t)k0t * BK))[0];
  int4 c1 = ((const int4*)(qbase + (size_t)k0t * BK))[1];
  float amax = ambase[k0t];

  for (int kt = k0t; kt < ktEnd; ++kt) {
    // A: 8 async 1KB/wave issues -> 32 KB tile
#pragma unroll
    for (int i = 0; i < 8; ++i) {
      const ushort* g = xbf + (size_t)(i * 32 + arow) * INF + kt * BK + acol;
      async_cp16(g, &Abuf[(i * 256 + w * 64) * 8]);
    }
    // B: dequant current regs, 1x ds_write_b128
    uint4 d;
    d.x = dq2(c0.x, c0.y, amax, tbits);
    d.y = dq2(c0.z, c0.w, amax, tbits);
    d.z = dq2(c1.x, c1.y, amax, tbits);
    d.w = dq2(c1.z, c1.w, amax, tbits);
    *(uint4*)&Bbuf[(brow * 8 + (bq ^ (brow & 7))) * 8] = d;
    // prefetch next iteration's codes (latency overlaps the A copies the barrier drains)
    if (kt + 1 < ktEnd) {
      c0 = ((const int4*)(qbase + (size_t)(kt + 1) * BK))[0];
      c1 = ((const int4*)(qbase + (size_t)(kt + 1) * BK))[1];
      amax = ambase[kt + 1];
    }
    __syncthreads();
#pragma unroll
    for (int ks = 0; ks < 2; ++ks) {
      bf16x8 a[4], b[2];
#pragma unroll
      for (int mt = 0; mt < 4; ++mt) a[mt] = *(const bf16x8*)&Abuf[aoff[ks][mt]];
#pragma unroll
      for (int nt = 0; nt < 2; ++nt) b[nt] = *(const bf16x8*)&Bbuf[boff[ks][nt]];
#pragma unroll
      for (int mt = 0; mt < 4; ++mt)
#pragma unroll
        for (int nt = 0; nt < 2; ++nt)
          acc[mt][nt] = __builtin_amdgcn_mfma_f32_16x16x32_bf16(a[mt], b[nt], acc[mt][nt], 0, 0, 0);
    }
    __syncthreads();
  }

  if (split == 0) {
    // lora extension: A tile from xa2 [256,64], B tile from lBbf rows [n0,n0+32)
#pragma unroll
    for (int i = 0; i < 8; ++i) {
      const ushort* g = xa2 + (i * 32 + arow) * 64 + acol;
      async_cp16(g, &Abuf[(i * 256 + w * 64) * 8]);
    }
    const ushort* g = lBbf + (size_t)(n0 + arow) * 64 + acol;
    async_cp16(g, &Bbuf[(w * 64) * 8]);
    __syncthreads();
#pragma unroll
    for (int ks = 0; ks < 2; ++ks) {
      bf16x8 a[4], b[2];
#pragma unroll
      for (int mt = 0; mt < 4; ++mt) a[mt] = *(const bf16x8*)&Abuf[aoff[ks][mt]];
#pragma unroll
      for (int nt = 0; nt < 2; ++nt) b[nt] = *(const bf16x8*)&Bbuf[boff[ks][nt]];
#pragma unroll
      for (int mt = 0; mt < 4; ++mt)
#pragma unroll
        for (int nt = 0; nt < 2; ++nt)
          acc[mt][nt] = __builtin_amdgcn_mfma_f32_16x16x32_bf16(a[mt], b[nt], acc[mt][nt], 0, 0, 0);
    }
    __syncthreads();
  }

  // epilogue: C/D layout col=lane&15, row=(lane>>4)*4+reg
  // *** each split writes its OWN partial slice ***
  float* dst = dest + (size_t)split * TOK * OUTF;
#pragma unroll
  for (int mt = 0; mt < 4; ++mt) {
#pragma unroll
    for (int nt = 0; nt < 2; ++nt) {
      int col = n0 + nt * 16 + (l & 15);
#pragma unroll
      for (int r = 0; r < 4; ++r) {
        int row = w * 64 + mt * 16 + (l >> 4) * 4 + r;
        dst[(size_t)row * OUTF + col] = acc[mt][nt][r];
      }
    }
  }
}

// kernel 4: sum K-split partials -> out
__global__ void reduce_kernel(const float4* __restrict__ part, float4* __restrict__ out,
                              int ks) {
  const int QN = TOK * OUTF / 4;
  int i = blockIdx.x * blockDim.x + threadIdx.x;
  if (i < QN) {
    float4 s = part[i];
    for (int s2 = 1; s2 < ks; ++s2) {
      float4 p = part[(size_t)s2 * QN + i];
      s.x += p.x; s.y += p.y; s.z += p.z; s.w += p.w;
    }
    out[i] = s;
  }
}

extern "C" void kernel_launch(void* const* d_in, const int* in_sizes, int n_in,
                              void* d_out, int out_size, void* d_ws, size_t ws_size,
                              hipStream_t stream) {
  const float* x = (const float*)d_in[0];
  const int* qc = (const int*)d_in[1];
  const float* am = (const float*)d_in[2];
  const float* lA = (const float*)d_in[3];
  const float* lB = (const float*)d_in[4];
  float* out = (float*)d_out;

  const size_t off_lB = (size_t)TOK * INF * 2;            // 2 MB
  const size_t off_xa2 = off_lB + (size_t)OUTF * 64 * 2;  // +1.34 MB
  const size_t off_part = off_xa2 + (size_t)TOK * 64 * 2; // +32 KB = 3,538,944 (16B aligned)
  const size_t part_bytes = (size_t)TOK * OUTF * 4;       // 11.27 MB per split

  ushort* xbf = (ushort*)d_ws;
  ushort* lBbf = (ushort*)((char*)d_ws + off_lB);
  ushort* xa2 = (ushort*)((char*)d_ws + off_xa2);
  float* part = (float*)((char*)d_ws + off_part);

  int ks = 1;
  if (ws_size >= off_part + 4 * part_bytes) ks = 4;
  else if (ws_size >= off_part + 2 * part_bytes) ks = 2;
  float* dest = (ks == 1) ? out : part;

  prep_kernel<<<1024, 256, 0, stream>>>((const float4*)x, (const float4*)lB,
                                        (ushort4*)xbf, (ushort4*)lBbf);
  xa_kernel<<<TOK, 1024, 0, stream>>>(x, lA, xa2);
  gemm_kernel<<<NTILES * ks, 256, 0, stream>>>(qc, am, xbf, lBbf, xa2, dest, NKT / ks);
  if (ks > 1)
    reduce_kernel<<<(TOK * OUTF / 4 + 255) / 256, 256, 0, stream>>>((const float4*)part,
                                                                    (float4*)out, ks);
}